// Round 1
// baseline (641.753 us; speedup 1.0000x reference)
//
#include <hip/hip_runtime.h>
#include <hip/hip_bf16.h>

#define NUM_E 64
#define D_K 512
#define D_N 512
#define BM 128
#define BN 128
#define BK 64
#define KPAD 72            // 144 B row stride: 16B-aligned, odd quad step -> conflict-free
#define MAX_TILES 576      // T/BM + E worst case
#define NT_N (D_N / BN)    // 4
#define GRID_X (MAX_TILES * NT_N)  // 2304, divisible by 8 -> bijective XCD swizzle

typedef __bf16 bf16x8 __attribute__((ext_vector_type(8)));
typedef float f32x16 __attribute__((ext_vector_type(16)));
typedef float f32x4 __attribute__((ext_vector_type(4)));
typedef unsigned int u32;
typedef unsigned short u16;

__device__ __forceinline__ int imin(int a, int b) { return a < b ? a : b; }

// Build per-M-tile descriptors so no tile crosses a group boundary.
__global__ void build_tiles_kernel(const int* __restrict__ gs,
                                   int* __restrict__ cnt,
                                   int* __restrict__ desc) {
    int e = threadIdx.x;
    if (e >= NUM_E) return;
    int row = 0, toff = 0;
    for (int i = 0; i < e; ++i) {
        int g = gs[i];
        row += g;
        toff += (g + BM - 1) / BM;
    }
    int g = gs[e];
    int nt = (g + BM - 1) / BM;
    for (int i = 0; i < nt; ++i) {
        int b = 3 * (toff + i);
        desc[b]     = e;
        desc[b + 1] = row + i * BM;
        desc[b + 2] = imin(BM, g - i * BM);
    }
    if (e == NUM_E - 1) cnt[0] = toff + nt;
}

// fp32 -> bf16 hi (round-nearest) + bf16 lo (truncated residual).
__device__ __forceinline__ void cvt_split(float a, u32 &hi, u32 &lo) {
    u32 u  = __float_as_uint(a);
    u32 rh = (u + 0x7FFFu + ((u >> 16) & 1u)) & 0xFFFF0000u;
    hi = rh >> 16;
    float res = a - __uint_as_float(rh);
    lo = __float_as_uint(res) >> 16;
}

__global__ void __launch_bounds__(256, 2)
grouped_gemm_kernel(const float* __restrict__ X, const float* __restrict__ W,
                    const float* __restrict__ bias, const int* __restrict__ cnt,
                    const int* __restrict__ desc, float* __restrict__ out) {
    extern __shared__ u16 lds[];
    u16* Ahi = lds;
    u16* Alo = Ahi + BM * KPAD;
    u16* Bhi = Alo + BM * KPAD;
    u16* Blo = Bhi + BM * KPAD;

    // XCD-aware bijective swizzle (2304 % 8 == 0)
    int bid = blockIdx.x;
    int s = (bid & 7) * (GRID_X / 8) + (bid >> 3);
    int tile  = s >> 2;
    int ntile = s & 3;
    if (tile >= cnt[0]) return;

    int expert = desc[3 * tile];
    int row0   = desc[3 * tile + 1];
    int rows   = desc[3 * tile + 2];
    int n0 = ntile * BN;

    const int tid  = threadIdx.x;
    const int lane = tid & 63;
    const int wid  = tid >> 6;
    const int wm = wid >> 1;   // wave row 0..1 (64-row half)
    const int wn = wid & 1;    // wave col 0..1 (64-col half)
    const int lr = lane & 31;
    const int kg = lane >> 5;  // k-group: +8 elements

    const float* Wp = W + (size_t)expert * D_K * D_N;

    f32x16 acc[2][2];
    #pragma unroll
    for (int i = 0; i < 2; ++i)
        #pragma unroll
        for (int j = 0; j < 2; ++j)
            #pragma unroll
            for (int r = 0; r < 16; ++r)
                acc[i][j][r] = 0.0f;

    for (int kt = 0; kt < D_K / BK; ++kt) {
        int k0 = kt * BK;

        // ---- stage A (BM x BK), row-major [m][k], split into hi/lo
        #pragma unroll
        for (int it = 0; it < 8; ++it) {
            int idx = it * 256 + tid;
            int m = idx >> 4;      // 0..127
            int q = idx & 15;      // k-quad 0..15
            f32x4 v;
            if (m < rows) {
                v = *(const f32x4*)(X + (size_t)(row0 + m) * D_K + k0 + q * 4);
            } else {
                v[0] = v[1] = v[2] = v[3] = 0.0f;
            }
            u32 h[4], l[4];
            #pragma unroll
            for (int j = 0; j < 4; ++j) cvt_split(v[j], h[j], l[j]);
            uint2 hp, lp;
            hp.x = h[0] | (h[1] << 16); hp.y = h[2] | (h[3] << 16);
            lp.x = l[0] | (l[1] << 16); lp.y = l[2] | (l[3] << 16);
            *(uint2*)(Ahi + m * KPAD + q * 4) = hp;
            *(uint2*)(Alo + m * KPAD + q * 4) = lp;
        }

        // ---- stage B transposed (BN x BK): thread owns (n, 4 consecutive k)
        #pragma unroll
        for (int it = 0; it < 8; ++it) {
            int idx = it * 256 + tid;
            int n  = idx & 127;    // 0..127
            int kb = idx >> 7;     // 0..15 -> k = kb*4 + j
            const float* bp = Wp + (size_t)(k0 + kb * 4) * D_N + n0 + n;
            u32 h[4], l[4];
            #pragma unroll
            for (int j = 0; j < 4; ++j) {
                float b = bp[(size_t)j * D_N];
                cvt_split(b, h[j], l[j]);
            }
            uint2 hp, lp;
            hp.x = h[0] | (h[1] << 16); hp.y = h[2] | (h[3] << 16);
            lp.x = l[0] | (l[1] << 16); lp.y = l[2] | (l[3] << 16);
            *(uint2*)(Bhi + n * KPAD + kb * 4) = hp;
            *(uint2*)(Blo + n * KPAD + kb * 4) = lp;
        }
        __syncthreads();

        // ---- compute: 4 k-steps of 16, 2x2 fragments, 3 passes (hh, hl, lh)
        #pragma unroll
        for (int ks = 0; ks < BK / 16; ++ks) {
            bf16x8 ah[2], al[2], bh[2], bl[2];
            #pragma unroll
            for (int f = 0; f < 2; ++f) {
                int aoff = (wm * 64 + f * 32 + lr) * KPAD + ks * 16 + kg * 8;
                ah[f] = *(const bf16x8*)(Ahi + aoff);
                al[f] = *(const bf16x8*)(Alo + aoff);
                int boff = (wn * 64 + f * 32 + lr) * KPAD + ks * 16 + kg * 8;
                bh[f] = *(const bf16x8*)(Bhi + boff);
                bl[f] = *(const bf16x8*)(Blo + boff);
            }
            #pragma unroll
            for (int i = 0; i < 2; ++i)
                #pragma unroll
                for (int j = 0; j < 2; ++j) {
                    acc[i][j] = __builtin_amdgcn_mfma_f32_32x32x16_bf16(ah[i], bh[j], acc[i][j], 0, 0, 0);
                    acc[i][j] = __builtin_amdgcn_mfma_f32_32x32x16_bf16(ah[i], bl[j], acc[i][j], 0, 0, 0);
                    acc[i][j] = __builtin_amdgcn_mfma_f32_32x32x16_bf16(al[i], bh[j], acc[i][j], 0, 0, 0);
                }
        }
        __syncthreads();
    }

    // ---- epilogue: bias add + store (C/D: col=lane&31, row=(r&3)+8*(r>>2)+4*(lane>>5))
    #pragma unroll
    for (int j = 0; j < 2; ++j) {
        int col = n0 + wn * 64 + j * 32 + lr;
        float bv = bias[col];
        #pragma unroll
        for (int i = 0; i < 2; ++i) {
            #pragma unroll
            for (int r = 0; r < 16; ++r) {
                int lm = wm * 64 + i * 32 + (r & 3) + 8 * (r >> 2) + 4 * kg;
                if (lm < rows)
                    out[(size_t)(row0 + lm) * D_N + col] = acc[i][j][r] + bv;
            }
        }
    }
}

extern "C" void kernel_launch(void* const* d_in, const int* in_sizes, int n_in,
                              void* d_out, int out_size, void* d_ws, size_t ws_size,
                              hipStream_t stream) {
    const float* X    = (const float*)d_in[0];
    const float* W    = (const float*)d_in[1];
    const float* bias = (const float*)d_in[2];
    const int*   gs   = (const int*)d_in[3];
    float* out = (float*)d_out;

    int* cnt  = (int*)d_ws;
    int* desc = cnt + 4;   // 16 B after cnt; needs 576*3*4 = 6912 B

    hipLaunchKernelGGL(build_tiles_kernel, dim3(1), dim3(64), 0, stream, gs, cnt, desc);

    const size_t lds_bytes = (size_t)4 * BM * KPAD * sizeof(u16);  // 73728
    hipLaunchKernelGGL(grouped_gemm_kernel, dim3(GRID_X), dim3(256), lds_bytes, stream,
                       X, W, bias, cnt, desc, out);
}

// Round 4
// 460.794 us; speedup vs baseline: 1.3927x; 1.3927x over previous
//
#include <hip/hip_runtime.h>
#include <hip/hip_bf16.h>

#define NUM_E 64
#define D_K 512
#define D_N 512
#define BM 128
#define BN 128
#define MAX_TILES 576              // T/BM + E worst case
#define GRID_X (MAX_TILES * 4)     // 2304, divisible by 8 -> bijective XCD swizzle

typedef __bf16 bf16x8 __attribute__((ext_vector_type(8)));
typedef float f32x16 __attribute__((ext_vector_type(16)));
typedef float f32x4 __attribute__((ext_vector_type(4)));
typedef unsigned int u32;
typedef unsigned short u16;

__device__ __forceinline__ int imin(int a, int b) { return a < b ? a : b; }

// async global->LDS, 16B per lane. LDS dest must be wave-uniform base.
__device__ __forceinline__ void gll16(const void* g, void* l) {
    __builtin_amdgcn_global_load_lds(
        (const __attribute__((address_space(1))) u32*)(uintptr_t)g,
        (__attribute__((address_space(3))) u32*)(uintptr_t)l, 16, 0, 0);
}

// fp32 -> bf16 hi (round-nearest) + bf16 lo (truncated residual). Same as round 1.
__device__ __forceinline__ void cvt_split(float a, u32 &hi, u32 &lo) {
    u32 u  = __float_as_uint(a);
    u32 rh = (u + 0x7FFFu + ((u >> 16) & 1u)) & 0xFFFF0000u;
    hi = rh >> 16;
    float res = a - __uint_as_float(rh);
    lo = __float_as_uint(res) >> 16;
}

// ---------------- tile descriptors (no tile crosses a group boundary) -------
__global__ void build_tiles_kernel(const int* __restrict__ gs,
                                   int* __restrict__ cnt,
                                   int* __restrict__ desc) {
    int e = threadIdx.x;
    if (e >= NUM_E) return;
    int row = 0, toff = 0;
    for (int i = 0; i < e; ++i) {
        int g = gs[i];
        row += g;
        toff += (g + BM - 1) / BM;
    }
    int g = gs[e];
    int nt = (g + BM - 1) / BM;
    for (int i = 0; i < nt; ++i) {
        int b = 3 * (toff + i);
        desc[b]     = e;
        desc[b + 1] = row + i * BM;
        desc[b + 2] = imin(BM, g - i * BM);
    }
    if (e == NUM_E - 1) cnt[0] = toff + nt;
}

// ---------------- convert X: [T][512] f32 -> [T][1024] bf16 (hi | lo) -------
__global__ void convert_x_kernel(const float* __restrict__ X, u16* __restrict__ Xc,
                                 int nquads) {
    int idx = blockIdx.x * blockDim.x + threadIdx.x;
    int stride = gridDim.x * blockDim.x;
    for (int q = idx; q < nquads; q += stride) {
        int row = q >> 7;            // 128 f32x4 per row
        int c4  = (q & 127) * 4;
        f32x4 v = *(const f32x4*)(X + (size_t)q * 4);
        u32 h[4], l[4];
        #pragma unroll
        for (int j = 0; j < 4; ++j) cvt_split(v[j], h[j], l[j]);
        uint2 hp, lp;
        hp.x = h[0] | (h[1] << 16); hp.y = h[2] | (h[3] << 16);
        lp.x = l[0] | (l[1] << 16); lp.y = l[2] | (l[3] << 16);
        *(uint2*)(Xc + (size_t)row * 1024 + c4)       = hp;
        *(uint2*)(Xc + (size_t)row * 1024 + 512 + c4) = lp;
    }
}

// -------- convert+transpose W: [e][k][n] f32 -> [e][n][1024] bf16 (hi | lo) --
__global__ void convert_w_kernel(const float* __restrict__ W, u16* __restrict__ Wc) {
    __shared__ u16 Thi[64 * 68];
    __shared__ u16 Tlo[64 * 68];
    int bid = blockIdx.x;
    int e  = bid >> 6;
    int ti = (bid >> 3) & 7;   // k-block
    int tj = bid & 7;          // n-block
    int tid = threadIdx.x;

    const float* Wp = W + (size_t)e * D_K * D_N;
    #pragma unroll
    for (int it = 0; it < 4; ++it) {
        int kl = it * 16 + (tid >> 4);       // 0..63
        int nl = (tid & 15) * 4;             // 0..60
        f32x4 v = *(const f32x4*)(Wp + (size_t)(ti * 64 + kl) * D_N + tj * 64 + nl);
        u32 h[4], l[4];
        #pragma unroll
        for (int j = 0; j < 4; ++j) cvt_split(v[j], h[j], l[j]);
        uint2 hp, lp;
        hp.x = h[0] | (h[1] << 16); hp.y = h[2] | (h[3] << 16);
        lp.x = l[0] | (l[1] << 16); lp.y = l[2] | (l[3] << 16);
        *(uint2*)(Thi + kl * 68 + nl) = hp;
        *(uint2*)(Tlo + kl * 68 + nl) = lp;
    }
    __syncthreads();
    #pragma unroll
    for (int it = 0; it < 4; ++it) {
        int nl = it * 16 + (tid >> 4);       // 0..63
        int kq = tid & 15;                   // 0..15 -> 4 k's each
        u32 h[4], l[4];
        #pragma unroll
        for (int j = 0; j < 4; ++j) {
            h[j] = Thi[(kq * 4 + j) * 68 + nl];
            l[j] = Tlo[(kq * 4 + j) * 68 + nl];
        }
        uint2 hp, lp;
        hp.x = h[0] | (h[1] << 16); hp.y = h[2] | (h[3] << 16);
        lp.x = l[0] | (l[1] << 16); lp.y = l[2] | (l[3] << 16);
        u16* outp = Wc + ((size_t)e << 19) + (size_t)(tj * 64 + nl) * 1024 + ti * 64;
        *(uint2*)(outp + kq * 4)       = hp;
        *(uint2*)(outp + 512 + kq * 4) = lp;
    }
}

// ---------------- main GEMM: bf16, K' = 1536 (hh, h*lo, lo*h segments) -------
__global__ void __launch_bounds__(256, 3)
gemm_split_kernel(const u16* __restrict__ Xc, const u16* __restrict__ Wc,
                  const float* __restrict__ bias, const int* __restrict__ cnt,
                  const int* __restrict__ desc, float* __restrict__ out, int T) {
    __shared__ u16 As[BM * 64];   // linear [128][64], XOR-swizzled content
    __shared__ u16 Bs[BN * 64];

    int bid = blockIdx.x;
    int s = (bid & 7) * (GRID_X / 8) + (bid >> 3);   // bijective XCD swizzle
    int tile  = s >> 2;
    int ntile = s & 3;
    if (tile >= cnt[0]) return;

    int expert = desc[3 * tile];
    int row0   = desc[3 * tile + 1];
    int rows   = desc[3 * tile + 2];
    int n0 = ntile * BN;

    const int tid  = threadIdx.x;
    const int lane = tid & 63;
    const int wid  = tid >> 6;
    const int wm = wid >> 1, wn = wid & 1;
    const int lr = lane & 31, kg = lane >> 5;

    // staging geometry: chunk = c*256 + tid; row = chunk>>3; j = chunk&7
    // LDS stays linear; SOURCE col-byte is XOR-swizzled (rule #21).
    int aoff[4], boff[4], ldsb[4];
    #pragma unroll
    for (int c = 0; c < 4; ++c) {
        int chunk = c * 256 + tid;
        int r = chunk >> 3, j = chunk & 7;
        int cb = (j * 16) ^ ((r & 7) << 4);          // swizzled source byte-in-row
        int ar = imin(row0 + r, T - 1);              // clamp (padded tail rows)
        aoff[c] = ar * 1024 + (cb >> 1);
        boff[c] = (expert << 19) + (n0 + r) * 1024 + (cb >> 1);
        ldsb[c] = (c * 256 + wid * 64) * 16;         // wave-uniform LDS byte base
    }

    f32x16 acc[2][2];
    #pragma unroll
    for (int i = 0; i < 2; ++i)
        #pragma unroll
        for (int j = 0; j < 2; ++j)
            #pragma unroll
            for (int r = 0; r < 16; ++r) acc[i][j][r] = 0.0f;

    for (int t = 0; t < 24; ++t) {
        int tt = t & 7, seg = t >> 3;
        int acol = tt * 64 + (seg == 2 ? 512 : 0);   // Al for seg 2
        int bcol = tt * 64 + (seg == 1 ? 512 : 0);   // Bl for seg 1
        #pragma unroll
        for (int c = 0; c < 4; ++c) {
            gll16(Xc + aoff[c] + acol, (char*)As + ldsb[c]);
            gll16(Wc + boff[c] + bcol, (char*)Bs + ldsb[c]);
        }
        __syncthreads();   // drains vmcnt -> staged data visible

        #pragma unroll
        for (int ks = 0; ks < 4; ++ks) {
            int kb = ks * 32 + kg * 16;              // byte offset in 128B row
            bf16x8 af[2], bb[2];
            #pragma unroll
            for (int f = 0; f < 2; ++f) {
                int ra = wm * 64 + f * 32 + lr;
                af[f] = *(const bf16x8*)((const char*)As + ra * 128 + (kb ^ ((ra & 7) << 4)));
                int rb = wn * 64 + f * 32 + lr;
                bb[f] = *(const bf16x8*)((const char*)Bs + rb * 128 + (kb ^ ((rb & 7) << 4)));
            }
            #pragma unroll
            for (int i = 0; i < 2; ++i)
                #pragma unroll
                for (int j = 0; j < 2; ++j)
                    acc[i][j] = __builtin_amdgcn_mfma_f32_32x32x16_bf16(af[i], bb[j], acc[i][j], 0, 0, 0);
        }
        __syncthreads();   // protect LDS from next-step staging
    }

    // epilogue: col=lane&31, row=(r&3)+8*(r>>2)+4*(lane>>5)
    #pragma unroll
    for (int j = 0; j < 2; ++j) {
        int col = n0 + wn * 64 + j * 32 + lr;
        float bv = bias[col];
        #pragma unroll
        for (int i = 0; i < 2; ++i) {
            #pragma unroll
            for (int r = 0; r < 16; ++r) {
                int lm = wm * 64 + i * 32 + (r & 3) + 8 * (r >> 2) + 4 * kg;
                if (lm < rows)
                    out[(size_t)(row0 + lm) * D_N + col] = acc[i][j][r] + bv;
            }
        }
    }
}

// ---------------- round-1 fallback (used only if ws too small) ---------------
#define KPAD 72
__global__ void __launch_bounds__(256, 2)
grouped_gemm_fallback(const float* __restrict__ X, const float* __restrict__ W,
                      const float* __restrict__ bias, const int* __restrict__ cnt,
                      const int* __restrict__ desc, float* __restrict__ out) {
    extern __shared__ u16 lds[];
    u16* Ahi = lds;
    u16* Alo = Ahi + BM * KPAD;
    u16* Bhi = Alo + BM * KPAD;
    u16* Blo = Bhi + BM * KPAD;

    int bid = blockIdx.x;
    int s = (bid & 7) * (GRID_X / 8) + (bid >> 3);
    int tile  = s >> 2;
    int ntile = s & 3;
    if (tile >= cnt[0]) return;

    int expert = desc[3 * tile];
    int row0   = desc[3 * tile + 1];
    int rows   = desc[3 * tile + 2];
    int n0 = ntile * BN;

    const int tid  = threadIdx.x;
    const int lane = tid & 63;
    const int wid  = tid >> 6;
    const int wm = wid >> 1, wn = wid & 1;
    const int lr = lane & 31, kg = lane >> 5;

    const float* Wp = W + (size_t)expert * D_K * D_N;

    f32x16 acc[2][2];
    #pragma unroll
    for (int i = 0; i < 2; ++i)
        #pragma unroll
        for (int j = 0; j < 2; ++j)
            #pragma unroll
            for (int r = 0; r < 16; ++r) acc[i][j][r] = 0.0f;

    for (int kt = 0; kt < D_K / 64; ++kt) {
        int k0 = kt * 64;
        #pragma unroll
        for (int it = 0; it < 8; ++it) {
            int idx = it * 256 + tid;
            int m = idx >> 4, q = idx & 15;
            f32x4 v;
            if (m < rows) v = *(const f32x4*)(X + (size_t)(row0 + m) * D_K + k0 + q * 4);
            else          v[0] = v[1] = v[2] = v[3] = 0.0f;
            u32 h[4], l[4];
            #pragma unroll
            for (int j = 0; j < 4; ++j) cvt_split(v[j], h[j], l[j]);
            uint2 hp, lp;
            hp.x = h[0] | (h[1] << 16); hp.y = h[2] | (h[3] << 16);
            lp.x = l[0] | (l[1] << 16); lp.y = l[2] | (l[3] << 16);
            *(uint2*)(Ahi + m * KPAD + q * 4) = hp;
            *(uint2*)(Alo + m * KPAD + q * 4) = lp;
        }
        #pragma unroll
        for (int it = 0; it < 8; ++it) {
            int idx = it * 256 + tid;
            int n = idx & 127, kb = idx >> 7;
            const float* bp = Wp + (size_t)(k0 + kb * 4) * D_N + n0 + n;
            u32 h[4], l[4];
            #pragma unroll
            for (int j = 0; j < 4; ++j) { float b = bp[(size_t)j * D_N]; cvt_split(b, h[j], l[j]); }
            uint2 hp, lp;
            hp.x = h[0] | (h[1] << 16); hp.y = h[2] | (h[3] << 16);
            lp.x = l[0] | (l[1] << 16); lp.y = l[2] | (l[3] << 16);
            *(uint2*)(Bhi + n * KPAD + kb * 4) = hp;
            *(uint2*)(Blo + n * KPAD + kb * 4) = lp;
        }
        __syncthreads();
        #pragma unroll
        for (int ks = 0; ks < 4; ++ks) {
            bf16x8 ah[2], al[2], bh[2], bl[2];
            #pragma unroll
            for (int f = 0; f < 2; ++f) {
                int aoff2 = (wm * 64 + f * 32 + lr) * KPAD + ks * 16 + kg * 8;
                ah[f] = *(const bf16x8*)(Ahi + aoff2);
                al[f] = *(const bf16x8*)(Alo + aoff2);
                int boff2 = (wn * 64 + f * 32 + lr) * KPAD + ks * 16 + kg * 8;
                bh[f] = *(const bf16x8*)(Bhi + boff2);
                bl[f] = *(const bf16x8*)(Blo + boff2);
            }
            #pragma unroll
            for (int i = 0; i < 2; ++i)
                #pragma unroll
                for (int j = 0; j < 2; ++j) {
                    acc[i][j] = __builtin_amdgcn_mfma_f32_32x32x16_bf16(ah[i], bh[j], acc[i][j], 0, 0, 0);
                    acc[i][j] = __builtin_amdgcn_mfma_f32_32x32x16_bf16(ah[i], bl[j], acc[i][j], 0, 0, 0);
                    acc[i][j] = __builtin_amdgcn_mfma_f32_32x32x16_bf16(al[i], bh[j], acc[i][j], 0, 0, 0);
                }
        }
        __syncthreads();
    }
    #pragma unroll
    for (int j = 0; j < 2; ++j) {
        int col = n0 + wn * 64 + j * 32 + lr;
        float bv = bias[col];
        #pragma unroll
        for (int i = 0; i < 2; ++i) {
            #pragma unroll
            for (int r = 0; r < 16; ++r) {
                int lm = wm * 64 + i * 32 + (r & 3) + 8 * (r >> 2) + 4 * kg;
                if (lm < rows)
                    out[(size_t)(row0 + lm) * D_N + col] = acc[i][j][r] + bv;
            }
        }
    }
}

extern "C" void kernel_launch(void* const* d_in, const int* in_sizes, int n_in,
                              void* d_out, int out_size, void* d_ws, size_t ws_size,
                              hipStream_t stream) {
    const float* X    = (const float*)d_in[0];
    const float* W    = (const float*)d_in[1];
    const float* bias = (const float*)d_in[2];
    const int*   gs   = (const int*)d_in[3];
    float* out = (float*)d_out;

    int T = in_sizes[0] / D_K;                       // 65536

    int* cnt  = (int*)d_ws;
    int* desc = cnt + 4;                             // desc: 576*3*4 = 6912 B
    hipLaunchKernelGGL(build_tiles_kernel, dim3(1), dim3(64), 0, stream, gs, cnt, desc);

    size_t x_bytes = (size_t)T * 1024 * sizeof(u16);          // 128 MiB
    size_t w_bytes = (size_t)NUM_E * D_N * 1024 * sizeof(u16); // 64 MiB
    size_t need = 8192 + x_bytes + w_bytes;

    if (ws_size >= need) {
        u16* Xc = (u16*)((char*)d_ws + 8192);
        u16* Wc = (u16*)((char*)d_ws + 8192 + x_bytes);

        int nquads = T * (D_K / 4);
        hipLaunchKernelGGL(convert_x_kernel, dim3(4096), dim3(256), 0, stream, X, Xc, nquads);
        hipLaunchKernelGGL(convert_w_kernel, dim3(NUM_E * 64), dim3(256), 0, stream, W, Wc);
        hipLaunchKernelGGL(gemm_split_kernel, dim3(GRID_X), dim3(256), 0, stream,
                           Xc, Wc, bias, cnt, desc, out, T);
    } else {
        const size_t lds_bytes = (size_t)4 * BM * KPAD * sizeof(u16);
        hipLaunchKernelGGL(grouped_gemm_fallback, dim3(GRID_X), dim3(256), lds_bytes, stream,
                           X, W, bias, cnt, desc, out);
    }
}